// Round 1
// baseline (313.157 us; speedup 1.0000x reference)
//
#include <hip/hip_runtime.h>
#include <math.h>

// ---------------- problem constants ----------------
#define NROWS 4096
#define DIM   512
#define SPLITS 16                 // column splits (flash-style split-K over columns)
#define CPS   (NROWS / SPLITS)    // 256 columns per split
#define JT    64                  // columns per j-tile (4 MFMA col-frags)
#define NJT   (CPS / JT)          // 4 j-tiles per split
#define KSTEPS (DIM / 32)         // 16 MFMA K-steps
#define BM    64                  // rows per workgroup (4 waves * 16 rows)
#define ROWBLKS (NROWS / BM)      // 64

typedef __bf16 bf16x8 __attribute__((ext_vector_type(8)));
typedef float  f32x4  __attribute__((ext_vector_type(4)));

// ---------------- kernel 1: row-normalize to bf16 ----------------
__global__ __launch_bounds__(64)
void normalize_kernel(const float* __restrict__ X, const float* __restrict__ Y,
                      __bf16* __restrict__ Xn, __bf16* __restrict__ Yn)
{
    const int row  = blockIdx.x;
    const int lane = threadIdx.x;  // 0..63
    const float* src = blockIdx.y ? Y : X;
    __bf16*      dst = blockIdx.y ? Yn : Xn;

    const float4* s4 = reinterpret_cast<const float4*>(src + (size_t)row * DIM);
    float4 v0 = s4[lane * 2 + 0];
    float4 v1 = s4[lane * 2 + 1];
    float ss = v0.x*v0.x + v0.y*v0.y + v0.z*v0.z + v0.w*v0.w
             + v1.x*v1.x + v1.y*v1.y + v1.z*v1.z + v1.w*v1.w;
    #pragma unroll
    for (int m = 1; m < 64; m <<= 1) ss += __shfl_xor(ss, m);
    const float scale = 1.0f / fmaxf(sqrtf(ss), 1e-8f);  // eps clamp like F.cosine_similarity

    bf16x8 o;
    o[0] = (__bf16)(v0.x * scale); o[1] = (__bf16)(v0.y * scale);
    o[2] = (__bf16)(v0.z * scale); o[3] = (__bf16)(v0.w * scale);
    o[4] = (__bf16)(v1.x * scale); o[5] = (__bf16)(v1.y * scale);
    o[6] = (__bf16)(v1.z * scale); o[7] = (__bf16)(v1.w * scale);
    *reinterpret_cast<bf16x8*>(dst + (size_t)row * DIM + lane * 8) = o;
}

// ---------------- kernel 2: fused gram + online softmax-KL partials ----------------
// logits: a = -S_t[i][j], b = -S_p[i][j]  (the reference's "1 -" cancels in log_softmax)
// per row, per split, accumulate: m_a, S=sum e^{a-m_a}, U=sum e^{a-m_a}*a,
//                                 V=sum e^{a-m_a}*b, m_b, Sb=sum e^{b-m_b}
__global__ __launch_bounds__(256, 4)
void gram_kl_kernel(const __bf16* __restrict__ Xn, const __bf16* __restrict__ Yn,
                    float* __restrict__ partials)
{
    const int wid  = threadIdx.x >> 6;
    const int lane = threadIdx.x & 63;
    const int rowblk = blockIdx.x & (ROWBLKS - 1);
    const int split  = blockIdx.x / ROWBLKS;

    const int r0   = rowblk * BM + wid * 16;       // this wave's 16 rows
    const int arow = r0 + (lane & 15);             // A fragment row
    const int kseg = (lane >> 4) * 8;              // k offset within a 32-wide K step

    // online state for 4 C-rows per lane (replicated across each 16-lane group)
    float m_a[4], s_a[4], u_a[4], v_a[4], m_b[4], s_b[4];
    #pragma unroll
    for (int r = 0; r < 4; ++r) {
        m_a[r] = -INFINITY; m_b[r] = -INFINITY;
        s_a[r] = 0.f; u_a[r] = 0.f; v_a[r] = 0.f; s_b[r] = 0.f;
    }

    const size_t arow_off = (size_t)arow * DIM + kseg;

    for (int jt = 0; jt < NJT; ++jt) {
        const int jb = split * CPS + jt * JT;

        f32x4 accT[4], accP[4];
        #pragma unroll
        for (int f = 0; f < 4; ++f) {
            accT[f] = f32x4{0.f, 0.f, 0.f, 0.f};
            accP[f] = f32x4{0.f, 0.f, 0.f, 0.f};
        }

        #pragma unroll
        for (int ks = 0; ks < KSTEPS; ++ks) {
            const bf16x8 axf = *reinterpret_cast<const bf16x8*>(Xn + arow_off + ks * 32);
            const bf16x8 ayf = *reinterpret_cast<const bf16x8*>(Yn + arow_off + ks * 32);
            #pragma unroll
            for (int f = 0; f < 4; ++f) {
                const size_t boff = (size_t)(jb + f * 16 + (lane & 15)) * DIM + ks * 32 + kseg;
                const bf16x8 bxf = *reinterpret_cast<const bf16x8*>(Xn + boff);
                const bf16x8 byf = *reinterpret_cast<const bf16x8*>(Yn + boff);
                accT[f] = __builtin_amdgcn_mfma_f32_16x16x32_bf16(axf, bxf, accT[f], 0, 0, 0);
                accP[f] = __builtin_amdgcn_mfma_f32_16x16x32_bf16(ayf, byf, accP[f], 0, 0, 0);
            }
        }

        // epilogue: C layout col = lane&15 (within frag f), row = (lane>>4)*4 + r
        #pragma unroll
        for (int r = 0; r < 4; ++r) {
            float a0 = -accT[0][r], a1 = -accT[1][r], a2 = -accT[2][r], a3 = -accT[3][r];
            float b0 = -accP[0][r], b1 = -accP[1][r], b2 = -accP[2][r], b3 = -accP[3][r];

            float tma = fmaxf(fmaxf(a0, a1), fmaxf(a2, a3));
            float tmb = fmaxf(fmaxf(b0, b1), fmaxf(b2, b3));
            #pragma unroll
            for (int m = 1; m <= 8; m <<= 1) {
                tma = fmaxf(tma, __shfl_xor(tma, m));
                tmb = fmaxf(tmb, __shfl_xor(tmb, m));
            }
            const float mna = fmaxf(m_a[r], tma);
            const float mnb = fmaxf(m_b[r], tmb);

            const float e0 = expf(a0 - mna), e1 = expf(a1 - mna);
            const float e2 = expf(a2 - mna), e3 = expf(a3 - mna);
            const float g0 = expf(b0 - mnb), g1 = expf(b1 - mnb);
            const float g2 = expf(b2 - mnb), g3 = expf(b3 - mnb);

            float ps = (e0 + e1) + (e2 + e3);
            float pu = e0 * a0 + e1 * a1 + e2 * a2 + e3 * a3;
            float pv = e0 * b0 + e1 * b1 + e2 * b2 + e3 * b3;
            float pq = (g0 + g1) + (g2 + g3);
            #pragma unroll
            for (int m = 1; m <= 8; m <<= 1) {
                ps += __shfl_xor(ps, m);
                pu += __shfl_xor(pu, m);
                pv += __shfl_xor(pv, m);
                pq += __shfl_xor(pq, m);
            }

            const float sca = expf(m_a[r] - mna);  // 0 on first tile (m=-inf)
            const float scb = expf(m_b[r] - mnb);
            s_a[r] = s_a[r] * sca + ps;
            u_a[r] = u_a[r] * sca + pu;
            v_a[r] = v_a[r] * sca + pv;
            s_b[r] = s_b[r] * scb + pq;
            m_a[r] = mna;
            m_b[r] = mnb;
        }
    }

    // write per-(row, split) partials; state is replicated over lane&15 -> lane 0 of each group writes
    if ((lane & 15) == 0) {
        #pragma unroll
        for (int r = 0; r < 4; ++r) {
            const int row = r0 + (lane >> 4) * 4 + r;
            float* p = partials + ((size_t)row * SPLITS + split) * 6;
            p[0] = m_a[r]; p[1] = s_a[r]; p[2] = u_a[r];
            p[3] = v_a[r]; p[4] = m_b[r]; p[5] = s_b[r];
        }
    }
}

// ---------------- kernel 3: merge split partials -> per-row KL ----------------
__global__ __launch_bounds__(256)
void merge_kernel(const float* __restrict__ partials, float* __restrict__ kl)
{
    const int row = blockIdx.x * 256 + threadIdx.x;
    if (row >= NROWS) return;
    const float* p = partials + (size_t)row * SPLITS * 6;

    float M = -INFINITY, Mb = -INFINITY;
    #pragma unroll
    for (int s = 0; s < SPLITS; ++s) {
        M  = fmaxf(M,  p[s * 6 + 0]);
        Mb = fmaxf(Mb, p[s * 6 + 4]);
    }
    float S = 0.f, U = 0.f, V = 0.f, Sb = 0.f;
    #pragma unroll
    for (int s = 0; s < SPLITS; ++s) {
        const float w = expf(p[s * 6 + 0] - M);
        S  += p[s * 6 + 1] * w;
        U  += p[s * 6 + 2] * w;
        V  += p[s * 6 + 3] * w;
        Sb += p[s * 6 + 5] * expf(p[s * 6 + 4] - Mb);
    }
    // kl_i = E_t[a] - E_t[b] - lse(a) + lse(b)
    kl[row] = (U - V) / S - (M + logf(S)) + (Mb + logf(Sb));
}

// ---------------- kernel 4: deterministic mean reduction ----------------
__global__ __launch_bounds__(256)
void reduce_kernel(const float* __restrict__ kl, float* __restrict__ out)
{
    __shared__ float lds[4];
    float acc = 0.f;
    for (int i = threadIdx.x; i < NROWS; i += 256) acc += kl[i];
    #pragma unroll
    for (int m = 1; m < 64; m <<= 1) acc += __shfl_xor(acc, m);
    if ((threadIdx.x & 63) == 0) lds[threadIdx.x >> 6] = acc;
    __syncthreads();
    if (threadIdx.x == 0) {
        out[0] = (lds[0] + lds[1] + lds[2] + lds[3]) / (float)NROWS;
    }
}

// ---------------- launch ----------------
extern "C" void kernel_launch(void* const* d_in, const int* in_sizes, int n_in,
                              void* d_out, int out_size, void* d_ws, size_t ws_size,
                              hipStream_t stream)
{
    const float* X = (const float*)d_in[0];   // cosine_distance_latent (target)
    const float* Y = (const float*)d_in[1];   // mse_latent (predicted)
    float* out = (float*)d_out;

    char* ws = (char*)d_ws;
    const size_t mat_bytes = (size_t)NROWS * DIM * sizeof(__bf16);  // 4 MiB each
    __bf16* Xn = (__bf16*)ws;
    __bf16* Yn = (__bf16*)(ws + mat_bytes);
    float* partials = (float*)(ws + 2 * mat_bytes);                          // 4096*16*6 f32 = 1.5 MiB
    float* kl = (float*)(ws + 2 * mat_bytes + (size_t)NROWS * SPLITS * 6 * sizeof(float));

    normalize_kernel<<<dim3(NROWS, 2), 64, 0, stream>>>(X, Y, Xn, Yn);
    gram_kl_kernel<<<ROWBLKS * SPLITS, 256, 0, stream>>>(Xn, Yn, partials);
    merge_kernel<<<NROWS / 256, 256, 0, stream>>>(partials, kl);
    reduce_kernel<<<1, 256, 0, stream>>>(kl, out);
}

// Round 2
// 65.424 us; speedup vs baseline: 4.7866x; 4.7866x over previous
//
#include <hip/hip_runtime.h>
#include <math.h>

// ---------------- problem constants ----------------
#define NROWS 4096
#define DIM   512
#define NSPLIT 16                 // column splits across blocks
#define BN    (NROWS / NSPLIT)    // 256 cols per block
#define JT    128                 // cols per j-tile (one accumulation phase)
#define NJT   (BN / JT)           // 2
#define BM    128                 // rows per block
#define ROWBLKS (NROWS / BM)      // 32
#define KSTEPS (DIM / 32)         // 16 K-steps of 32
#define NSTEPS (NJT * KSTEPS)     // 32 pipelined stage/compute steps

typedef __bf16 bf16x8 __attribute__((ext_vector_type(8)));
typedef float  f32x4  __attribute__((ext_vector_type(4)));

#define GL16(G, L) __builtin_amdgcn_global_load_lds( \
    (const __attribute__((address_space(1))) void*)(G), \
    (__attribute__((address_space(3))) void*)(L), 16, 0, 0)

// ---------------- kernel 1: row-normalize to bf16 ----------------
__global__ __launch_bounds__(64)
void normalize_kernel(const float* __restrict__ X, const float* __restrict__ Y,
                      __bf16* __restrict__ Xn, __bf16* __restrict__ Yn)
{
    const int row  = blockIdx.x;
    const int lane = threadIdx.x;  // 0..63
    const float* src = blockIdx.y ? Y : X;
    __bf16*      dst = blockIdx.y ? Yn : Xn;

    const float4* s4 = reinterpret_cast<const float4*>(src + (size_t)row * DIM);
    float4 v0 = s4[lane * 2 + 0];
    float4 v1 = s4[lane * 2 + 1];
    float ss = v0.x*v0.x + v0.y*v0.y + v0.z*v0.z + v0.w*v0.w
             + v1.x*v1.x + v1.y*v1.y + v1.z*v1.z + v1.w*v1.w;
    #pragma unroll
    for (int m = 1; m < 64; m <<= 1) ss += __shfl_xor(ss, m);
    const float scale = 1.0f / fmaxf(sqrtf(ss), 1e-8f);

    bf16x8 o;
    o[0] = (__bf16)(v0.x * scale); o[1] = (__bf16)(v0.y * scale);
    o[2] = (__bf16)(v0.z * scale); o[3] = (__bf16)(v0.w * scale);
    o[4] = (__bf16)(v1.x * scale); o[5] = (__bf16)(v1.y * scale);
    o[6] = (__bf16)(v1.z * scale); o[7] = (__bf16)(v1.w * scale);
    *reinterpret_cast<bf16x8*>(dst + (size_t)row * DIM + lane * 8) = o;
}

// ---------------- kernel 2: fused gram + exp-sum partials ----------------
// Swapped-operand MFMA: C[j, i] = sum_k Jfrag[j,k] * Ifrag[i,k]
//   C layout: col (lane&15) = i, row ((lane>>4)*4 + reg) = j  -> j is lane-local.
// Logits a = -simT, b = -simP bounded in [-1,1] -> no max tracking needed:
//   S = sum e^a, U = sum e^a * a, V = sum e^a * b, Q = sum e^b  (plain sums, mergeable)
__global__ __launch_bounds__(256, 2)
void gram_kl_kernel(const __bf16* __restrict__ Xn, const __bf16* __restrict__ Yn,
                    float4* __restrict__ partials)
{
    // LDS: [buf][panel: 0=I_X, 1=I_Y, 2=J_X, 3=J_Y][128 rows][64 B], 64 KiB total
    __shared__ char lds[2][4][8192];

    const int tid  = threadIdx.x;
    const int wid  = tid >> 6;
    const int lane = tid & 63;

    // XCD-aware swizzle: colsplit pinned to XCD (blockIdx % 8 == XCD round-robin)
    const int g = blockIdx.x;
    const int xcd = g & 7;
    const int q = g >> 3;                 // 0..63
    const int split  = xcd + 8 * (q & 1); // 0..15
    const int rowblk = q >> 1;            // 0..31

    const int i0 = rowblk * BM;
    const int j0 = split * BN;

    const int wi = wid >> 1;   // wave's i-quadrant (0..1): i = i0 + wi*64 + ...
    const int wj = wid & 1;    // wave's j-quadrant (0..1)

    // ---- staging source offsets (pre-swizzled global so LDS dest stays linear) ----
    // LDS unit u (16B): row = u>>2, slot = u&3 holds global seg = slot ^ ((row>>1)&3)
    const int u0 = tid, u1 = tid + 256;
    const int so0 = ((u0 >> 2) << 10) + ((((u0 & 3) ^ ((u0 >> 3) & 3))) << 4);
    const int so1 = ((u1 >> 2) << 10) + ((((u1 & 3) ^ ((u1 >> 3) & 3))) << 4);
    const int d0 = wid * 1024;            // wave-uniform LDS dest bases
    const int d1 = 4096 + wid * 1024;

    const char* bx = (const char*)Xn;
    const char* by = (const char*)Yn;

    auto STAGE = [&](int buf, int s) {
        const int ks = s & 15;
        const int jt = s >> 4;
        const size_t ioff = ((size_t)i0 << 10) + ((size_t)ks << 6);
        const size_t joff = ((size_t)(j0 + jt * JT) << 10) + ((size_t)ks << 6);
        char* l = &lds[buf][0][0];
        GL16(bx + ioff + so0, l + 0 * 8192 + d0);
        GL16(bx + ioff + so1, l + 0 * 8192 + d1);
        GL16(by + ioff + so0, l + 1 * 8192 + d0);
        GL16(by + ioff + so1, l + 1 * 8192 + d1);
        GL16(bx + joff + so0, l + 2 * 8192 + d0);
        GL16(bx + joff + so1, l + 2 * 8192 + d1);
        GL16(by + joff + so0, l + 3 * 8192 + d0);
        GL16(by + joff + so1, l + 3 * 8192 + d1);
    };

    // ---- fragment read offset (swizzled): row = f*16 + (lane&15), seg = lane>>4 ----
    const int rd_off = ((lane & 15) << 6) + ((((lane >> 4) ^ ((lane >> 1) & 3))) << 4);

    f32x4 accT[4][4];  // [fj][fi]
    f32x4 accP[4][4];
    float sS[4], sU[4], sV[4], sQ[4];
    #pragma unroll
    for (int fi = 0; fi < 4; ++fi) { sS[fi] = 0.f; sU[fi] = 0.f; sV[fi] = 0.f; sQ[fi] = 0.f; }
    #pragma unroll
    for (int fj = 0; fj < 4; ++fj)
        #pragma unroll
        for (int fi = 0; fi < 4; ++fi) {
            accT[fj][fi] = f32x4{0.f, 0.f, 0.f, 0.f};
            accP[fj][fi] = f32x4{0.f, 0.f, 0.f, 0.f};
        }

    STAGE(0, 0);
    __syncthreads();           // buf0 staged (implicit vmcnt(0))

    int cur = 0;
    for (int s = 0; s < NSTEPS; ++s) {
        if (s + 1 < NSTEPS) STAGE(cur ^ 1, s + 1);   // prefetch next step

        // ---- compute current buffer ----
        const char* l = &lds[cur][0][0];
        bf16x8 aX[4], aY[4], bX[4], bY[4];
        #pragma unroll
        for (int fj = 0; fj < 4; ++fj) {
            const int fo = ((wj * 4 + fj) << 10) + rd_off;
            aX[fj] = *reinterpret_cast<const bf16x8*>(l + 2 * 8192 + fo);
            aY[fj] = *reinterpret_cast<const bf16x8*>(l + 3 * 8192 + fo);
        }
        #pragma unroll
        for (int fi = 0; fi < 4; ++fi) {
            const int fo = ((wi * 4 + fi) << 10) + rd_off;
            bX[fi] = *reinterpret_cast<const bf16x8*>(l + 0 * 8192 + fo);
            bY[fi] = *reinterpret_cast<const bf16x8*>(l + 1 * 8192 + fo);
        }
        #pragma unroll
        for (int fj = 0; fj < 4; ++fj)
            #pragma unroll
            for (int fi = 0; fi < 4; ++fi) {
                accT[fj][fi] = __builtin_amdgcn_mfma_f32_16x16x32_bf16(aX[fj], bX[fi], accT[fj][fi], 0, 0, 0);
                accP[fj][fi] = __builtin_amdgcn_mfma_f32_16x16x32_bf16(aY[fj], bY[fi], accP[fj][fi], 0, 0, 0);
            }

        // ---- end of a j-tile: fold 32 similarity values per lane into the 4 sums ----
        if ((s & 15) == 15) {
            #pragma unroll
            for (int fi = 0; fi < 4; ++fi) {
                float S = 0.f, U = 0.f, V = 0.f, Q = 0.f;
                #pragma unroll
                for (int fj = 0; fj < 4; ++fj)
                    #pragma unroll
                    for (int r = 0; r < 4; ++r) {
                        const float a = -accT[fj][fi][r];
                        const float b = -accP[fj][fi][r];
                        const float ea = __expf(a);
                        const float eb = __expf(b);
                        S += ea; U += ea * a; V += ea * b; Q += eb;
                    }
                sS[fi] += S; sU[fi] += U; sV[fi] += V; sQ[fi] += Q;
                #pragma unroll
                for (int fj = 0; fj < 4; ++fj) {
                    accT[fj][fi] = f32x4{0.f, 0.f, 0.f, 0.f};
                    accP[fj][fi] = f32x4{0.f, 0.f, 0.f, 0.f};
                }
            }
        }

        __syncthreads();       // next buffer staged + LDS reads drained
        cur ^= 1;
    }

    // ---- reduce across the 4 j-subgroups (lane>>4), then write partials ----
    #pragma unroll
    for (int fi = 0; fi < 4; ++fi) {
        #pragma unroll
        for (int m = 16; m <= 32; m <<= 1) {
            sS[fi] += __shfl_xor(sS[fi], m);
            sU[fi] += __shfl_xor(sU[fi], m);
            sV[fi] += __shfl_xor(sV[fi], m);
            sQ[fi] += __shfl_xor(sQ[fi], m);
        }
    }
    if (lane < 16) {
        const int slot = split * 2 + wj;   // 32 slots per row
        #pragma unroll
        for (int fi = 0; fi < 4; ++fi) {
            const int row = i0 + wi * 64 + fi * 16 + lane;
            partials[(size_t)row * 32 + slot] = float4{sS[fi], sU[fi], sV[fi], sQ[fi]};
        }
    }
}

// ---------------- kernel 3: merge partial sums -> per-row KL ----------------
__global__ __launch_bounds__(256)
void merge_kernel(const float4* __restrict__ partials, float* __restrict__ kl)
{
    const int row = blockIdx.x * 256 + threadIdx.x;
    if (row >= NROWS) return;
    float S = 0.f, U = 0.f, V = 0.f, Q = 0.f;
    #pragma unroll
    for (int s = 0; s < 32; ++s) {
        const float4 p = partials[(size_t)row * 32 + s];
        S += p.x; U += p.y; V += p.z; Q += p.w;
    }
    // kl_i = E_t[a] - E_t[b] - lse(a) + lse(b), with a = -simT, b = -simP
    kl[row] = (U - V) / S - logf(S) + logf(Q);
}

// ---------------- kernel 4: deterministic mean reduction ----------------
__global__ __launch_bounds__(256)
void reduce_kernel(const float* __restrict__ kl, float* __restrict__ out)
{
    __shared__ float ldsr[4];
    float acc = 0.f;
    for (int i = threadIdx.x; i < NROWS; i += 256) acc += kl[i];
    #pragma unroll
    for (int m = 1; m < 64; m <<= 1) acc += __shfl_xor(acc, m);
    if ((threadIdx.x & 63) == 0) ldsr[threadIdx.x >> 6] = acc;
    __syncthreads();
    if (threadIdx.x == 0) {
        out[0] = (ldsr[0] + ldsr[1] + ldsr[2] + ldsr[3]) / (float)NROWS;
    }
}

// ---------------- launch ----------------
extern "C" void kernel_launch(void* const* d_in, const int* in_sizes, int n_in,
                              void* d_out, int out_size, void* d_ws, size_t ws_size,
                              hipStream_t stream)
{
    const float* X = (const float*)d_in[0];   // cosine_distance_latent (target)
    const float* Y = (const float*)d_in[1];   // mse_latent (predicted)
    float* out = (float*)d_out;

    char* ws = (char*)d_ws;
    const size_t mat_bytes = (size_t)NROWS * DIM * sizeof(__bf16);  // 4 MiB each
    __bf16* Xn = (__bf16*)ws;
    __bf16* Yn = (__bf16*)(ws + mat_bytes);
    float4* partials = (float4*)(ws + 2 * mat_bytes);               // 4096*32*16 B = 2 MiB
    float* kl = (float*)(ws + 2 * mat_bytes + (size_t)NROWS * 32 * sizeof(float4));

    normalize_kernel<<<dim3(NROWS, 2), 64, 0, stream>>>(X, Y, Xn, Yn);
    gram_kl_kernel<<<ROWBLKS * NSPLIT, 256, 0, stream>>>(Xn, Yn, partials);
    merge_kernel<<<NROWS / 256, 256, 0, stream>>>(partials, kl);
    reduce_kernel<<<1, 256, 0, stream>>>(kl, out);
}